// Round 10
// baseline (140.158 us; speedup 1.0000x reference)
//
#include <hip/hip_runtime.h>

// QuantLinear: out[8,11008] = x[8,4096] @ W[11008,4096]^T
// packed[i] (INT32, one per byte!) holds 2 nibbles: low = weight 2i, high = weight 2i+1;
// weight = (q-8)*scale[idx/32]. 2048 int32 per row of 4096 k; 128 scales per row.
//
// R10: R9's fat-request structure with CORRECT strided scale staging.
//   - weights: 8x dwordx4 per wave (2 tiles of 512 k x 4 rows; lane owns 8 consecutive k).
//   - scales: 2 coalesced dword loads per wave: lane -> (r = lane>>5, blk = lane&31) and
//     (r+2, blk), i.e. scales[(r0+r)*128 + kq/32 + blk] — 4 row-chunks of 32 at stride 128.
//     Parked in LDS as [row][blk], consumed via broadcast ds_read (lgkmcnt).
//   - per-wave VMEM requests: 18 (8 x-stage + 8 weights + 2 scales), vs 40 in R8.
//   Issue order: x loads first (oldest), then weights+scales; ds_write x waits only the
//   8 oldest -> weight loads stay in flight across the barrier; tiles consume in issue order.
//   Grid: 688 row-groups x split-K=4 = 2752 WGs x 256 thr. WG: 16 rows, one 1024-k quarter,
//   x[8][1024] = 32 KB LDS + 2 KB scale park.
//   Epilogue: 5-step shfl_xor tree + xor32; lanes 0-31 atomicAdd (out memset to 0).

#define OUT_F 11008
#define IN_F  4096

__global__ __launch_bounds__(256) void qlin_kernel(
    const float* __restrict__ x,
    const int*   __restrict__ packed,
    const float* __restrict__ scales,
    float*       __restrict__ out)
{
    const int tid  = threadIdx.x;
    const int lane = tid & 63;
    const int wave = tid >> 6;
    const int b    = blockIdx.x;
    const int q    = b & 3;                  // k-quarter
    const int g    = b >> 2;                 // row-group 0..687
    const int r0   = g * 16 + wave * 4;      // wave's 4 rows
    const int kq   = q * 1024;               // global k base of quarter

    __shared__ float xs[8 * 1024];           // staged x quarter (32 KB)
    __shared__ float sws[4 * 128];           // per-wave scale park (2 KB), [row][blk]

    // ---- 1) x loads FIRST: oldest entries in the vmcnt queue ----
    float4 xv[8];
    {
        const float* xg = x + kq;
#pragma unroll
        for (int i = 0; i < 8; ++i) {
            const int f  = tid + i * 256;         // float4 id 0..2047
            const int m  = f >> 8;
            const int kv = (f & 255) << 2;
            xv[i] = *(const float4*)(xg + m * IN_F + kv);
        }
    }

    // ---- 2) weight loads: 8x dwordx4 (2 tiles x 4 rows), then 2 scale dwords ----
    const int pb = r0 * 2048 + (kq >> 1) + lane * 4;   // int32 units; tile stride 256
    int4 wq[2][4];                                // [tile][row]
#pragma unroll
    for (int t = 0; t < 2; ++t)
#pragma unroll
        for (int r = 0; r < 4; ++r)
            wq[t][r] = *(const int4*)(packed + pb + r * 2048 + t * 256);

    // lane -> (row sr in {0,1}, block sblk); two loads cover rows {sr, sr+2}
    const int sr   = lane >> 5;                   // 0..1
    const int sblk = lane & 31;                   // 0..31
    const float s_a = scales[(r0 + sr)     * 128 + (kq >> 5) + sblk];
    const float s_b = scales[(r0 + 2 + sr) * 128 + (kq >> 5) + sblk];

    // ---- 3) stage x (waits only the 8 oldest loads) + park scales ----
#pragma unroll
    for (int i = 0; i < 8; ++i) {
        const int f  = tid + i * 256;
        const int m  = f >> 8;
        const int kv = (f & 255) << 2;
        *(float4*)(xs + m * 1024 + kv) = xv[i];
    }
    sws[wave * 128 + lane]      = s_a;            // rows 0-1: offset sr*32+sblk == lane
    sws[wave * 128 + 64 + lane] = s_b;            // rows 2-3
    __syncthreads();

    float acc[32];                                // acc[r*8 + m]
#pragma unroll
    for (int i = 0; i < 32; ++i) acc[i] = 0.f;

    const float* swb = sws + wave * 128;          // wave's scale park, [row][blk]

#pragma unroll
    for (int t = 0; t < 2; ++t) {                 // 2 tiles of 512 k, consumed in issue order
        // lane's 8 k live in one 32-k scale block: blk = t*16 + (lane>>2)
        float w[4][8];
#pragma unroll
        for (int r = 0; r < 4; ++r) {
            const float s  = swb[r * 32 + t * 16 + (lane >> 2)];  // broadcast ds_read
            const float ns = -8.f * s;
            const int4  p  = wq[t][r];
            w[r][0] = fmaf((float)(p.x & 15),        s, ns);
            w[r][1] = fmaf((float)((p.x >> 4) & 15), s, ns);
            w[r][2] = fmaf((float)(p.y & 15),        s, ns);
            w[r][3] = fmaf((float)((p.y >> 4) & 15), s, ns);
            w[r][4] = fmaf((float)(p.z & 15),        s, ns);
            w[r][5] = fmaf((float)((p.z >> 4) & 15), s, ns);
            w[r][6] = fmaf((float)(p.w & 15),        s, ns);
            w[r][7] = fmaf((float)((p.w >> 4) & 15), s, ns);
        }

        const int kl = t * 512 + lane * 8;        // local k in quarter (lane's 8 k)
#pragma unroll
        for (int m = 0; m < 8; ++m) {
            const float4 xa = *(const float4*)(xs + m * 1024 + kl);      // ds_read_b128
            const float4 xb = *(const float4*)(xs + m * 1024 + kl + 4);  // ds_read_b128
#pragma unroll
            for (int r = 0; r < 4; ++r) {
                float a = acc[r * 8 + m];
                a = fmaf(w[r][0], xa.x, a);
                a = fmaf(w[r][1], xa.y, a);
                a = fmaf(w[r][2], xa.z, a);
                a = fmaf(w[r][3], xa.w, a);
                a = fmaf(w[r][4], xb.x, a);
                a = fmaf(w[r][5], xb.y, a);
                a = fmaf(w[r][6], xb.z, a);
                a = fmaf(w[r][7], xb.w, a);
                acc[r * 8 + m] = a;
            }
        }
    }

    // ---- merge tree over 32 values: lane l ends with wave-total for index l&31 ----
#pragma unroll
    for (int s = 0; s < 5; ++s) {
        const int bit = (lane >> s) & 1;
        const int n = 16 >> s;
#pragma unroll
        for (int j = 0; j < n; ++j) {
            const float u = bit ? acc[2 * j + 1] : acc[2 * j];
            const float v = bit ? acc[2 * j]     : acc[2 * j + 1];
            acc[j] = u + __shfl_xor(v, 1 << s, 64);
        }
    }
    acc[0] += __shfl_xor(acc[0], 32, 64);

    if (lane < 32) {
        const int r = lane >> 3;                  // index l = r*8 + m
        const int m = lane & 7;
        atomicAdd(out + m * OUT_F + r0 + r, acc[0]);
    }
}

extern "C" void kernel_launch(void* const* d_in, const int* in_sizes, int n_in,
                              void* d_out, int out_size, void* d_ws, size_t ws_size,
                              hipStream_t stream) {
    const float* x      = (const float*)d_in[0];
    const int*   packed = (const int*)  d_in[1];
    const float* scales = (const float*)d_in[2];
    float*       out    = (float*)d_out;

    // split-K atomics accumulate into out -> zero it first (async, graph-capturable)
    hipMemsetAsync(out, 0, (size_t)out_size * sizeof(float), stream);

    dim3 grid((OUT_F / 16) * 4), block(256);      // 2752 WGs x 4 waves
    hipLaunchKernelGGL(qlin_kernel, grid, block, 0, stream,
                       x, packed, scales, out);
}